// Round 6
// baseline (653.082 us; speedup 1.0000x reference)
//
#include <hip/hip_runtime.h>
#include <hip/hip_fp16.h>
#include <math.h>
#include <type_traits>

#define DEVI __device__ __forceinline__

typedef __attribute__((ext_vector_type(8))) short bf16x8;
typedef __attribute__((ext_vector_type(4))) float f32x4;
typedef __attribute__((ext_vector_type(4))) unsigned int u32x4;
typedef unsigned short ushort_t;

DEVI unsigned int pack_bf16(float a, float b) {
  unsigned int ua = __float_as_uint(a), ub = __float_as_uint(b);
  ua = (ua + 0x7FFFu + ((ua >> 16) & 1u)) >> 16;   // RNE
  ub = (ub + 0x7FFFu + ((ub >> 16) & 1u)) >> 16;
  return ua | (ub << 16);
}

DEVI bf16x8 cvt_bf16x8(f32x4 lo, f32x4 hi) {
  unsigned int r0, r1, r2, r3;
  asm("v_cvt_pk_bf16_f32 %0, %1, %2" : "=v"(r0) : "v"(lo[0]), "v"(lo[1]));
  asm("v_cvt_pk_bf16_f32 %0, %1, %2" : "=v"(r1) : "v"(lo[2]), "v"(lo[3]));
  asm("v_cvt_pk_bf16_f32 %0, %1, %2" : "=v"(r2) : "v"(hi[0]), "v"(hi[1]));
  asm("v_cvt_pk_bf16_f32 %0, %1, %2" : "=v"(r3) : "v"(hi[2]), "v"(hi[3]));
  union { u32x4 u; bf16x8 v; } x;
  x.u = u32x4{r0, r1, r2, r3};
  return x.v;
}

// =======================================================================
// GEMM: C[M,N](+=bias) = A_fp32[M,K] * B_bf16[N,K]^T
// 128x128 tile, BK=32, 4 waves (64x64/wave), 3-buffer LDS ring (72KB,
// 2 blocks/CU) with 2-AHEAD prefetch + counted vmcnt(6): STAGE(t+2) ->
// compute(t) -> vmcnt(6) [t+1 landed, t+2 in flight] -> s_barrier.
// 16B-granule XOR swizzle (A: c^=row&7; B: c^=row&3). Linear gload_lds
// dest + pre-swizzled global source + swizzled ds_read (rule #21).
// K must be a multiple of 32.
// =======================================================================
template<int SPLITZ, bool DUALB, bool BIAS, typename OutT>
__global__ __launch_bounds__(256, 2) void bgemm(
    const float* __restrict__ A, const ushort_t* __restrict__ B0,
    const ushort_t* __restrict__ B1, const float* __restrict__ bias0,
    const float* __restrict__ bias1, OutT* __restrict__ C,
    int M, int N, int K, int nbn, int nbm)
{
  __shared__ __align__(16) char AsB[3 * 16384];   // A tile: 128 rows x 32 f32
  __shared__ __align__(16) char BsB[3 * 8192];    // B tile: 128 rows x 32 bf16
  const int tid = threadIdx.x, lane = tid & 63, wv = tid >> 6;

  // bijective XCD remap of flat block id (m204)
  const int nwg = gridDim.x;
  const int hw = blockIdx.x;
  const int q = nwg >> 3, r = nwg & 7;
  const int xcd = hw & 7, pos = hw >> 3;
  const int lid = (xcd < r ? xcd * (q + 1) : r * (q + 1) + (xcd - r) * q) + pos;
  const int bn = lid % nbn;
  const int t2 = lid / nbn;
  const int bm = t2 % nbm;
  const int z  = t2 / nbm;

  const ushort_t* B  = (DUALB && z == 1) ? B1 : B0;
  const float* bias  = (DUALB && z == 1) ? bias1 : bias0;

  const int ksteps = K >> 5;
  int kbBeg = 0, kbEnd = ksteps;
  if (SPLITZ > 1) {
    const int sz = (ksteps + SPLITZ - 1) / SPLITZ;
    kbBeg = z * sz;
    kbEnd = min(ksteps, kbBeg + sz);
  }

  const int wr = (wv >> 1) * 64, wc = (wv & 1) * 64;
  const int lrow = lane & 15, kg = lane >> 4;

  f32x4 acc[4][4];
#pragma unroll
  for (int i = 0; i < 4; ++i)
#pragma unroll
    for (int j = 0; j < 4; ++j) acc[i][j] = f32x4{0.f, 0.f, 0.f, 0.f};

  // ---- staging source pointers (pre-swizzled global columns)
  const int arow = lane >> 3;
  const int acol = ((lane & 7) ^ arow) << 2;         // float offset in [0,32)
  const float* aSrc[4];
#pragma unroll
  for (int j = 0; j < 4; ++j) {
    const int grow = min(bm * 128 + wv * 32 + j * 8 + arow, M - 1);
    aSrc[j] = A + (size_t)grow * (size_t)K + acol;
  }
  const int brow = lane >> 2;
  const int bcol = ((lane & 3) ^ (brow & 3)) << 3;   // bf16 offset in [0,32)
  const ushort_t* bSrc[2];
#pragma unroll
  for (int j = 0; j < 2; ++j) {
    const int grow = min(bn * 128 + wv * 32 + j * 16 + brow, N - 1);
    bSrc[j] = B + (size_t)grow * (size_t)K + bcol;
  }

  // ---- compute-side LDS byte offsets (k-independent at BK=32)
  int aoff0[4], aoff1[4], boff[4];
#pragma unroll
  for (int i = 0; i < 4; ++i) {
    const int ra = wr + i * 16 + lrow;
    aoff0[i] = ra * 128 + ((((kg << 1)    ) ^ (ra & 7)) << 4);
    aoff1[i] = ra * 128 + ((((kg << 1) | 1) ^ (ra & 7)) << 4);
    const int rb = wc + i * 16 + lrow;
    boff[i] = rb * 64 + ((kg ^ (rb & 3)) << 4);
  }

#define GEE_STAGE(kb, b) do {                                                 \
    const int k0_ = (kb) << 5;                                                \
    char* abase_ = AsB + (b) * 16384;                                         \
    char* bbase_ = BsB + (b) * 8192;                                          \
    _Pragma("unroll")                                                         \
    for (int j_ = 0; j_ < 4; ++j_)                                            \
      __builtin_amdgcn_global_load_lds(                                       \
          (const __attribute__((address_space(1))) void*)(aSrc[j_] + k0_),    \
          (__attribute__((address_space(3))) void*)(abase_ +                  \
              (wv * 4 + j_) * 1024), 16, 0, 0);                               \
    _Pragma("unroll")                                                         \
    for (int j_ = 0; j_ < 2; ++j_)                                            \
      __builtin_amdgcn_global_load_lds(                                       \
          (const __attribute__((address_space(1))) void*)(bSrc[j_] + k0_),    \
          (__attribute__((address_space(3))) void*)(bbase_ +                  \
              (wv * 2 + j_) * 1024), 16, 0, 0);                               \
  } while (0)

  // ---- prologue: stage tiles kbBeg (buf0) and kbBeg+1 (buf1)
  GEE_STAGE(kbBeg, 0);
  const bool two = (kbBeg + 1 < kbEnd);
  if (two) {
    GEE_STAGE(kbBeg + 1, 1);
    asm volatile("s_waitcnt vmcnt(6)" ::: "memory");   // buf0 landed
  } else {
    asm volatile("s_waitcnt vmcnt(0)" ::: "memory");
  }
  __builtin_amdgcn_s_barrier();

  int cur = 0;
  for (int t = kbBeg; t < kbEnd; ++t) {
    const bool s2 = (t + 2 < kbEnd);
    if (s2) {
      const int nb = (cur == 0) ? 2 : (cur == 1 ? 0 : 1);   // (cur+2)%3
      GEE_STAGE(t + 2, nb);
    }
    const char* ab = AsB + cur * 16384;
    const char* bb = BsB + cur * 8192;
    f32x4 alo[4], ahi[4];
    bf16x8 bfr[4];
#pragma unroll
    for (int i = 0; i < 4; ++i) {
      alo[i] = *(const f32x4*)(ab + aoff0[i]);
      ahi[i] = *(const f32x4*)(ab + aoff1[i]);
      bfr[i] = *(const bf16x8*)(bb + boff[i]);
    }
#pragma unroll
    for (int i = 0; i < 4; ++i) {
      const bf16x8 af = cvt_bf16x8(alo[i], ahi[i]);
#pragma unroll
      for (int j = 0; j < 4; ++j)
        acc[i][j] = __builtin_amdgcn_mfma_f32_16x16x32_bf16(af, bfr[j], acc[i][j], 0, 0, 0);
    }
    if (t + 1 < kbEnd) {
      if (s2) asm volatile("s_waitcnt vmcnt(6)" ::: "memory");  // t+1 landed
      else    asm volatile("s_waitcnt vmcnt(0)" ::: "memory");
      __builtin_amdgcn_s_barrier();
    }
    cur = (cur == 2) ? 0 : cur + 1;
  }
#undef GEE_STAGE

  const size_t zoff = (SPLITZ > 1 || DUALB) ? (size_t)z * (size_t)M * (size_t)N : 0;
#pragma unroll
  for (int i = 0; i < 4; ++i) {
#pragma unroll
    for (int j = 0; j < 4; ++j) {
      const int col = bn * 128 + wc + j * 16 + lrow;
      if (col >= N) continue;
      const int row0 = bm * 128 + wr + i * 16 + kg * 4;
      float bv = 0.f;
      if (BIAS) bv = bias[col];
#pragma unroll
      for (int rr = 0; rr < 4; ++rr) {
        const int gr = row0 + rr;
        if (gr < M) {
          const float v = acc[i][j][rr] + bv;
          if constexpr (std::is_same<OutT, __half>::value)
            C[zoff + (size_t)gr * (size_t)N + col] = __float2half(v);
          else
            C[zoff + (size_t)gr * (size_t)N + col] = v;
        }
      }
    }
  }
}

// ---------------- fp32 -> bf16 convert (8 elems/thread)
__global__ __launch_bounds__(256) void f2b(
    const float4* __restrict__ in, u32x4* __restrict__ out, int n8)
{
  const int i = blockIdx.x * 256 + threadIdx.x;
  if (i < n8) {
    const float4 a = in[2 * i], b = in[2 * i + 1];
    u32x4 o = { pack_bf16(a.x, a.y), pack_bf16(a.z, a.w),
                pack_bf16(b.x, b.y), pack_bf16(b.z, b.w) };
    out[i] = o;
  }
}

// ---------------- fused: sum 4 split-K partials + bias + LayerNorm + GELU + l2norm
__global__ __launch_bounds__(256) void gee_fuse_ln1(
    const float* __restrict__ P, const float* __restrict__ b_enc,
    const float* __restrict__ g1, const float* __restrict__ b1,
    float* __restrict__ hx)
{
  const int row = blockIdx.x, tid = threadIdx.x;
  __shared__ float red[16];
  const size_t MN = (size_t)4096 * 512;
  float v[2];
#pragma unroll
  for (int e = 0; e < 2; ++e) {
    const int c = tid + e * 256;
    const size_t o = (size_t)row * 512 + c;
    float s = b_enc[c];
#pragma unroll
    for (int qq = 0; qq < 4; ++qq) s += P[qq * MN + o];
    v[e] = s;
  }
  float a = v[0] + v[1];
  float b = v[0] * v[0] + v[1] * v[1];
#pragma unroll
  for (int o = 32; o > 0; o >>= 1) { a += __shfl_xor(a, o); b += __shfl_xor(b, o); }
  const int lane = tid & 63, wvi = tid >> 6;
  if (lane == 0) { red[wvi] = a; red[8 + wvi] = b; }
  __syncthreads();
  const float mu  = (red[0] + red[1] + red[2] + red[3]) * (1.f / 512.f);
  const float ex2 = (red[8] + red[9] + red[10] + red[11]) * (1.f / 512.f);
  const float inv = rsqrtf(ex2 - mu * mu + 1e-5f);
  float gl[2], ss = 0.f;
#pragma unroll
  for (int e = 0; e < 2; ++e) {
    const int c = tid + e * 256;
    const float y = (v[e] - mu) * inv * g1[c] + b1[c];
    const float t = 0.5f * y * (1.f + erff(y * 0.70710678118654752f));
    gl[e] = t; ss += t * t;
  }
  __syncthreads();
#pragma unroll
  for (int o = 32; o > 0; o >>= 1) ss += __shfl_xor(ss, o);
  if (lane == 0) red[wvi] = ss;
  __syncthreads();
  const float nrm = sqrtf(red[0] + red[1] + red[2] + red[3]);
  const float sc = 1.f / fmaxf(nrm, 1e-12f);
#pragma unroll
  for (int e = 0; e < 2; ++e)
    hx[(size_t)row * 512 + tid + e * 256] = gl[e] * sc;
}

// ---------------- row l2norm of raw e [20000,512] fp32 -> eb bf16
__global__ __launch_bounds__(256) void gee_l2rows(
    const float* __restrict__ ein, ushort_t* __restrict__ eb)
{
  const int row = blockIdx.x, tid = threadIdx.x;
  __shared__ float red[4];
  const float2* er = (const float2*)(ein + (size_t)row * 512);
  const float2 v = er[tid];
  float ss = v.x * v.x + v.y * v.y;
#pragma unroll
  for (int o = 32; o > 0; o >>= 1) ss += __shfl_xor(ss, o);
  if ((tid & 63) == 0) red[tid >> 6] = ss;
  __syncthreads();
  const float sc = 1.f / fmaxf(sqrtf(red[0] + red[1] + red[2] + red[3]), 1e-12f);
  ((unsigned int*)eb)[(size_t)row * 256 + tid] = pack_bf16(v.x * sc, v.y * sc);
}

// ---------------- per-row top-64: LDS byte-histogram select + compaction
__global__ __launch_bounds__(256) void gee_topk(
    const __half* __restrict__ scores, int* __restrict__ oidx, float* __restrict__ ow)
{
  constexpr int G = 20000, GP = G / 2, CAP = 2048, TCAP = 160;
  const int row = blockIdx.x, tid = threadIdx.x;
  const int lane = tid & 63, wv = tid >> 6;
  __shared__ int hist[4][256];
  __shared__ int cnt_ge[256];
  __shared__ int wtop[4];
  __shared__ unsigned int comp[CAP];   // (key<<16) | idx
  __shared__ int whist[4][16];
  __shared__ int sel[64];
  __shared__ int tie[TCAP];
  __shared__ int s_thr, s_above, s_cand, s_cnt, s_n1, s_n2;

  const unsigned int* srow32 =
      (const unsigned int*)((const ushort_t*)scores + (size_t)row * G);
  const ushort_t* srow16 = (const ushort_t*)srow32;

#pragma unroll
  for (int b = 0; b < 4; ++b) hist[b][tid] = 0;
  if (tid == 0) { s_cnt = 0; s_n1 = 0; s_n2 = 0; }
  __syncthreads();

  // ---- scan 1: per-wave-privatized 256-bin histogram of the top key byte
  for (int j0 = 0; j0 < GP; j0 += 256) {
    const int j = j0 + tid;
    if (j < GP) {
      const unsigned int p = srow32[j];
      // packed monotone map: per half, key = raw ^ (0x8000 + sign*0x7FFF)
      const unsigned int f = (((p >> 15) & 0x10001u) * 0x7FFFu) + 0x80008000u;
      const unsigned int k2 = p ^ f;
      atomicAdd(&hist[wv][(k2 >> 8) & 0xFFu], 1);
      atomicAdd(&hist[wv][k2 >> 24], 1);
    }
  }
  __syncthreads();
  // total per byte, then suffix-sum (Hillis-Steele): cnt_ge[b] = #elems with byte >= b
  cnt_ge[tid] = hist[0][tid] + hist[1][tid] + hist[2][tid] + hist[3][tid];
  __syncthreads();
  for (int off = 1; off < 256; off <<= 1) {
    const int add = (tid + off < 256) ? cnt_ge[tid + off] : 0;
    __syncthreads();
    cnt_ge[tid] += add;
    __syncthreads();
  }
  // threshold byte = largest b with cnt_ge[b] >= 64 (cnt_ge is non-increasing)
  {
    const unsigned long long m = __ballot(cnt_ge[tid] >= 64);
    if (lane == 0) wtop[wv] = m ? (wv * 64 + 63 - __clzll(m)) : -1;
  }
  __syncthreads();
  if (tid == 0) {
    const int thrB = max(max(wtop[0], wtop[1]), max(wtop[2], wtop[3]));
    s_cand  = cnt_ge[thrB];
    s_above = (thrB == 255) ? 0 : cnt_ge[thrB + 1];
    s_thr   = thrB << 8;
  }
  __syncthreads();

  const bool useComp = (s_cand <= CAP);
  const unsigned int thrB = ((unsigned int)s_thr) >> 8;

  // ---- scan 2: compact elements with byte >= thrB (exactly s_cand of them)
  if (useComp) {
    for (int j0 = 0; j0 < GP; j0 += 256) {
      const int j = j0 + tid;
      if (j < GP) {
        const unsigned int p = srow32[j];
        const unsigned int f = (((p >> 15) & 0x10001u) * 0x7FFFu) + 0x80008000u;
        const unsigned int k2 = p ^ f;
        const unsigned int lo = k2 & 0xFFFFu, hi = k2 >> 16;
        if ((lo >> 8) >= thrB) {
          const int pos = atomicAdd(&s_cnt, 1);
          comp[pos] = (lo << 16) | (unsigned)(2 * j);
        }
        if ((hi >> 8) >= thrB) {
          const int pos = atomicAdd(&s_cnt, 1);
          comp[pos] = (hi << 16) | (unsigned)(2 * j + 1);
        }
      }
    }
  }
  __syncthreads();
  const int Nloop = useComp ? s_cnt : G;

  // ---- nibble passes over compact list (or global fallback): bits [7:4], [3:0]
  for (int pass = 2; pass < 4; ++pass) {
    const int shift = 12 - 4 * pass;
    const unsigned int thr = (unsigned int)s_thr;
    const unsigned int pfx = thr >> (shift + 4);
    int c[16];
#pragma unroll
    for (int b = 0; b < 16; ++b) c[b] = 0;
    for (int j0 = 0; j0 < Nloop; j0 += 256) {
      const int j = j0 + tid;
      const bool ok = j < Nloop;
      unsigned int key;
      if (useComp) {
        key = ok ? (comp[j] >> 16) : 0u;
      } else {
        const unsigned int raw = ok ? (unsigned int)srow16[j] : 0u;
        key = (raw & 0x8000u) ? (0xFFFFu & ~raw) : (raw | 0x8000u);
      }
      const unsigned int nb = (ok && (key >> (shift + 4)) == pfx) ? ((key >> shift) & 15u) : 0xFFu;
#pragma unroll
      for (int b = 0; b < 16; ++b) c[b] += __popcll(__ballot(nb == (unsigned)b));
    }
    if (lane == 0) {
#pragma unroll
      for (int b = 0; b < 16; ++b) whist[wv][b] = c[b];
    }
    __syncthreads();
    if (tid == 0) {
      int run = s_above;
      for (int vv = 15; vv >= 0; --vv) {
        const int c4 = whist[0][vv] + whist[1][vv] + whist[2][vv] + whist[3][vv];
        if (run + c4 >= 64) { s_thr |= vv << shift; break; }
        run += c4;
      }
      s_above = run;
    }
    __syncthreads();
  }

  // ---- selection: key > kthr -> sel, == kthr -> tie
  const unsigned int kthr = (unsigned int)s_thr;
  for (int j0 = 0; j0 < Nloop; j0 += 256) {
    const int j = j0 + tid;
    if (j < Nloop) {
      unsigned int key, idx;
      if (useComp) {
        const unsigned int u = comp[j];
        key = u >> 16; idx = u & 0xFFFFu;
      } else {
        const unsigned int raw = (unsigned int)srow16[j];
        key = (raw & 0x8000u) ? (0xFFFFu & ~raw) : (raw | 0x8000u);
        idx = (unsigned)j;
      }
      if (key > kthr) {
        const int pos = atomicAdd(&s_n1, 1);
        sel[pos] = (int)idx;
      } else if (key == kthr) {
        const int pos = atomicAdd(&s_n2, 1);
        if (pos < TCAP) tie[pos] = (int)idx;
      }
    }
  }
  __syncthreads();
  if (tid == 0) {
    const int n1 = s_n1;
    const int n2 = min(s_n2, TCAP);
    const int need = 64 - n1;
    for (int rr = 0; rr < need; ++rr) {     // smallest indices (top_k tie-break)
      int best = 1 << 30, bj = 0;
      for (int j = 0; j < n2; ++j)
        if (tie[j] < best) { best = tie[j]; bj = j; }
      sel[n1 + rr] = best;
      tie[bj] = 1 << 30;
    }
  }
  __syncthreads();
  if (tid < 64) {
    const int idx = sel[tid];
    const float s = __half2float(scores[(size_t)row * G + idx]) * 10.0f;  // 1/T
    float m = s;
#pragma unroll
    for (int o = 32; o > 0; o >>= 1) m = fmaxf(m, __shfl_xor(m, o));
    const float w = __expf(s - m);
    float d = w;
#pragma unroll
    for (int o = 32; o > 0; o >>= 1) d += __shfl_xor(d, o);
    oidx[(size_t)row * 64 + tid] = idx;
    ow[(size_t)row * 64 + tid] = w / d;
  }
}

// ---------------- ctx[b] = sum_k attn_k * eb[idx_k]  (bf16 gather, fp32 accum)
__global__ __launch_bounds__(256) void gee_ctx(
    const int* __restrict__ idx, const float* __restrict__ w,
    const ushort_t* __restrict__ eb, float* __restrict__ ctx)
{
  const int row = blockIdx.x, tid = threadIdx.x;
  __shared__ int sidx[64];
  __shared__ float sw[64];
  if (tid < 64) { sidx[tid] = idx[(size_t)row * 64 + tid]; sw[tid] = w[(size_t)row * 64 + tid]; }
  __syncthreads();
  float a0 = 0.f, a1 = 0.f;
#pragma unroll 4
  for (int k = 0; k < 64; ++k) {
    const unsigned int pk = ((const unsigned int*)(eb + (size_t)sidx[k] * 512))[tid];
    const float wk = sw[k];
    a0 += wk * __uint_as_float(pk << 16);
    a1 += wk * __uint_as_float(pk & 0xFFFF0000u);
  }
  ((float2*)(ctx + (size_t)row * 512))[tid] = make_float2(a0, a1);
}

// ---------------- h_cell = (1+gamma)*h_x + beta
__global__ __launch_bounds__(256) void gee_film(
    const float4* __restrict__ gm, const float4* __restrict__ bt,
    const float4* __restrict__ hx, float4* __restrict__ hc, int n4)
{
  const int i = blockIdx.x * 256 + threadIdx.x;
  if (i < n4) {
    const float4 g = gm[i], b = bt[i], h = hx[i];
    float4 r;
    r.x = (1.f + g.x) * h.x + b.x;
    r.y = (1.f + g.y) * h.y + b.y;
    r.z = (1.f + g.z) * h.z + b.z;
    r.w = (1.f + g.w) * h.w + b.w;
    hc[i] = r;
  }
}

// ---------------- LN2 + exact GELU -> out [4096,1024]
__global__ __launch_bounds__(256) void gee_ln2(
    const float* __restrict__ h2, const float* __restrict__ g2,
    const float* __restrict__ b2, float* __restrict__ out)
{
  const int row = blockIdx.x, tid = threadIdx.x;
  __shared__ float red[16];
  float v[4];
  float a = 0.f, b = 0.f;
#pragma unroll
  for (int e = 0; e < 4; ++e) {
    v[e] = h2[(size_t)row * 1024 + tid + e * 256];
    a += v[e]; b += v[e] * v[e];
  }
#pragma unroll
  for (int o = 32; o > 0; o >>= 1) { a += __shfl_xor(a, o); b += __shfl_xor(b, o); }
  const int lane = tid & 63, wvi = tid >> 6;
  if (lane == 0) { red[wvi] = a; red[8 + wvi] = b; }
  __syncthreads();
  const float mu  = (red[0] + red[1] + red[2] + red[3]) * (1.f / 1024.f);
  const float ex2 = (red[8] + red[9] + red[10] + red[11]) * (1.f / 1024.f);
  const float inv = rsqrtf(ex2 - mu * mu + 1e-5f);
#pragma unroll
  for (int e = 0; e < 4; ++e) {
    const int c = tid + e * 256;
    const float y = (v[e] - mu) * inv * g2[c] + b2[c];
    out[(size_t)row * 1024 + c] = 0.5f * y * (1.f + erff(y * 0.70710678118654752f));
  }
}

extern "C" void kernel_launch(void* const* d_in, const int* in_sizes, int n_in,
                              void* d_out, int out_size, void* d_ws, size_t ws_size,
                              hipStream_t stream)
{
  const float* x       = (const float*)d_in[0];
  const float* g       = (const float*)d_in[1];
  const float* W_enc   = (const float*)d_in[2];
  const float* b_enc   = (const float*)d_in[3];
  const float* ln1_g   = (const float*)d_in[4];
  const float* ln1_b   = (const float*)d_in[5];
  const float* W_ga    = (const float*)d_in[6];
  const float* W_gamma = (const float*)d_in[7];
  const float* b_gamma = (const float*)d_in[8];
  const float* W_beta  = (const float*)d_in[9];
  const float* b_beta  = (const float*)d_in[10];
  const float* W_exp   = (const float*)d_in[11];
  const float* b_exp   = (const float*)d_in[12];
  const float* ln2_g   = (const float*)d_in[13];
  const float* ln2_b   = (const float*)d_in[14];
  float* out = (float*)d_out;

  char* ws = (char*)d_ws;
  constexpr size_t OFF_PART   = 0;            // 4*4096*512*4 = 33,554,432
  constexpr size_t OFF_SCORES = 0;            // 163,840,000 (after part dead)
  constexpr size_t OFF_GA     = 0;            // 8,388,608
  constexpr size_t OFF_BE     = 8388608;      // 8,388,608  (GA + M*N*4 for DUALB)
  constexpr size_t OFF_HC     = 16777216;     // 8,388,608
  constexpr size_t OFF_H2     = 25165824;     // 16,777,216
  constexpr size_t OFF_CTX    = 50331648;     // 8,388,608
  constexpr size_t OFF_WENCB  = 163840000;    // 20,480,000 (also eb later)
  constexpr size_t OFF_WGAB   = 184320000;    // 524,288
  constexpr size_t OFF_WGMB   = 184844288;    // 524,288
  constexpr size_t OFF_WBTB   = 185368576;    // 524,288
  constexpr size_t OFF_WEXB   = 185892864;    // 1,048,576
  constexpr size_t OFF_HX     = 186941440;    // 8,388,608
  constexpr size_t OFF_E      = 195330048;    // 40,960,000
  constexpr size_t OFF_TIDX   = 236290048;    // 1,048,576
  constexpr size_t OFF_TW     = 237338624;    // 1,048,576  -> total 238,387,200

  float*    part   = (float*)(ws + OFF_PART);
  __half*   scores = (__half*)(ws + OFF_SCORES);
  float*    ga     = (float*)(ws + OFF_GA);
  float*    be     = (float*)(ws + OFF_BE);
  float*    hc     = (float*)(ws + OFF_HC);
  float*    h2     = (float*)(ws + OFF_H2);
  float*    ctx    = (float*)(ws + OFF_CTX);
  ushort_t* wencb  = (ushort_t*)(ws + OFF_WENCB);
  ushort_t* eb     = (ushort_t*)(ws + OFF_WENCB);   // time-shared with wencb
  ushort_t* wgab   = (ushort_t*)(ws + OFF_WGAB);
  ushort_t* wgmb   = (ushort_t*)(ws + OFF_WGMB);
  ushort_t* wbtb   = (ushort_t*)(ws + OFF_WBTB);
  ushort_t* wexb   = (ushort_t*)(ws + OFF_WEXB);
  float*    hx     = (float*)(ws + OFF_HX);
  float*    e      = (float*)(ws + OFF_E);
  int*      tidx   = (int*)(ws + OFF_TIDX);
  float*    tw     = (float*)(ws + OFF_TW);

  // 0) weight converts fp32 -> bf16
  f2b<<<5000, 256, 0, stream>>>((const float4*)W_enc,   (u32x4*)wencb, 1280000);
  f2b<<<128,  256, 0, stream>>>((const float4*)W_ga,    (u32x4*)wgab,  32768);
  f2b<<<128,  256, 0, stream>>>((const float4*)W_gamma, (u32x4*)wgmb,  32768);
  f2b<<<128,  256, 0, stream>>>((const float4*)W_beta,  (u32x4*)wbtb,  32768);
  f2b<<<256,  256, 0, stream>>>((const float4*)W_exp,   (u32x4*)wexb,  65536);

  // 1) split-K=4 partials of x @ W_enc^T  -> part[4][4096][512]  (512 blk = 2/CU)
  bgemm<4, false, false, float><<<512, 256, 0, stream>>>(
      x, wencb, nullptr, nullptr, nullptr, part, 4096, 512, 20000, 4, 32);
  // 2) h_x = l2norm(gelu(LN1(sum partials + b_enc)))
  gee_fuse_ln1<<<4096, 256, 0, stream>>>(part, b_enc, ln1_g, ln1_b, hx);
  // 3) e_raw = g @ W_ga^T  [20000][512]
  bgemm<1, false, false, float><<<628, 256, 0, stream>>>(
      g, wgab, nullptr, nullptr, nullptr, e, 20000, 512, 512, 4, 157);
  // 4) eb = l2norm rows (bf16)
  gee_l2rows<<<20000, 256, 0, stream>>>(e, eb);
  // 5) scores = h_x @ eb^T  (fp16 raw cosine; /T applied in topk)
  bgemm<1, false, false, __half><<<5024, 256, 0, stream>>>(
      hx, eb, nullptr, nullptr, nullptr, scores, 4096, 20000, 512, 157, 32);
  // 6) top-64 + softmax weights
  gee_topk<<<4096, 256, 0, stream>>>(scores, tidx, tw);
  // 7) ctx = attn-weighted sum of eb rows
  gee_ctx<<<4096, 256, 0, stream>>>(tidx, tw, eb, ctx);
  // 8) FiLM gamma (z=0) / beta (z=1) in one launch
  bgemm<1, true, true, float><<<256, 256, 0, stream>>>(
      ctx, wgmb, wbtb, b_gamma, b_beta, ga, 4096, 512, 512, 4, 32);
  // 9) h_cell = (1+gamma)*h_x + beta
  gee_film<<<2048, 256, 0, stream>>>((const float4*)ga, (const float4*)be,
                                     (const float4*)hx, (float4*)hc, 524288);
  // 10) h2 = h_cell @ W_exp^T + b_exp
  bgemm<1, false, true, float><<<256, 256, 0, stream>>>(
      hc, wexb, nullptr, b_exp, nullptr, h2, 4096, 1024, 512, 8, 32);
  // 11) out = gelu(LN2(h2))
  gee_ln2<<<4096, 256, 0, stream>>>(h2, ln2_g, ln2_b, out);
}

// Round 7
// 539.957 us; speedup vs baseline: 1.2095x; 1.2095x over previous
//
#include <hip/hip_runtime.h>
#include <hip/hip_fp16.h>
#include <math.h>
#include <type_traits>

#define DEVI __device__ __forceinline__

typedef __attribute__((ext_vector_type(8))) short bf16x8;
typedef __attribute__((ext_vector_type(4))) float f32x4;
typedef __attribute__((ext_vector_type(4))) unsigned int u32x4;
typedef unsigned short ushort_t;

DEVI unsigned int pack_bf16(float a, float b) {
  unsigned int ua = __float_as_uint(a), ub = __float_as_uint(b);
  ua = (ua + 0x7FFFu + ((ua >> 16) & 1u)) >> 16;   // RNE
  ub = (ub + 0x7FFFu + ((ub >> 16) & 1u)) >> 16;
  return ua | (ub << 16);
}

DEVI bf16x8 cvt_bf16x8(f32x4 lo, f32x4 hi) {
  unsigned int r0, r1, r2, r3;
  asm("v_cvt_pk_bf16_f32 %0, %1, %2" : "=v"(r0) : "v"(lo[0]), "v"(lo[1]));
  asm("v_cvt_pk_bf16_f32 %0, %1, %2" : "=v"(r1) : "v"(lo[2]), "v"(lo[3]));
  asm("v_cvt_pk_bf16_f32 %0, %1, %2" : "=v"(r2) : "v"(hi[0]), "v"(hi[1]));
  asm("v_cvt_pk_bf16_f32 %0, %1, %2" : "=v"(r3) : "v"(hi[2]), "v"(hi[3]));
  union { u32x4 u; bf16x8 v; } x;
  x.u = u32x4{r0, r1, r2, r3};
  return x.v;
}

// =======================================================================
// GEMM: C[M,N](+=bias) = A[M,K] * B_bf16[N,K]^T,  A is fp32 OR bf16.
// 128x128 tile, BK=64, 4 waves (64x64/wave), SINGLE-buffered LDS,
// stage -> sync -> compute -> sync (r3 structure; proven best).
// fp32-A: As 32KB (12 gload_lds/step), LDS 48KB -> 3 blocks/CU.
// bf16-A: As 16KB (8 gload_lds/step),  LDS 32KB -> 4 blocks/CU.
// 16B-granule XOR swizzle; linear gload_lds dest + pre-swizzled global
// source + swizzled ds_read (rule #21). bf16-A requires K%64==0.
// =======================================================================
template<typename AT, int SPLITZ, bool DUALB, bool BIAS, typename OutT>
__global__ __launch_bounds__(256, sizeof(AT) == 2 ? 4 : 3) void bgemm(
    const AT* __restrict__ A, const ushort_t* __restrict__ B0,
    const ushort_t* __restrict__ B1, const float* __restrict__ bias0,
    const float* __restrict__ bias1, OutT* __restrict__ C,
    int M, int N, int K, int nbn, int nbm)
{
  constexpr bool AB16 = (sizeof(AT) == 2);
  __shared__ __align__(16) char AsB[AB16 ? 16384 : 32768];
  __shared__ __align__(16) char BsB[16384];
  const int tid = threadIdx.x, lane = tid & 63, wv = tid >> 6;

  // bijective XCD remap of flat block id (m204)
  const int nwg = gridDim.x;
  const int hw = blockIdx.x;
  const int q = nwg >> 3, r = nwg & 7;
  const int xcd = hw & 7, pos = hw >> 3;
  const int lid = (xcd < r ? xcd * (q + 1) : r * (q + 1) + (xcd - r) * q) + pos;
  const int bn = lid % nbn;
  const int t2 = lid / nbn;
  const int bm = t2 % nbm;
  const int z  = t2 / nbm;

  const ushort_t* B  = (DUALB && z == 1) ? B1 : B0;
  const float* bias  = (DUALB && z == 1) ? bias1 : bias0;

  const int ksteps = (K + 63) >> 6;
  int kbBeg = 0, kbEnd = ksteps;
  if (SPLITZ > 1) {
    const int sz = (ksteps + SPLITZ - 1) / SPLITZ;
    kbBeg = z * sz;
    kbEnd = min(ksteps, kbBeg + sz);
  }

  const int wr = (wv >> 1) * 64, wc = (wv & 1) * 64;
  const int lrow = lane & 15, kg = lane >> 4;

  f32x4 acc[4][4];
#pragma unroll
  for (int i = 0; i < 4; ++i)
#pragma unroll
    for (int j = 0; j < 4; ++j) acc[i][j] = f32x4{0.f, 0.f, 0.f, 0.f};

  // ---- staging source pointers (pre-swizzled global columns)
  const AT* aSrc[AB16 ? 4 : 8];
  int colAe;                       // A col offset in elements (for tail guard)
  if constexpr (AB16) {
    const int rA0 = wv * 8 + (lane >> 3);
    colAe = (((lane & 7) ^ (lane >> 3)) << 3);
#pragma unroll
    for (int j = 0; j < 4; ++j) {
      const int grow = min(bm * 128 + rA0 + j * 32, M - 1);
      aSrc[j] = A + (size_t)grow * (size_t)K + colAe;
    }
  } else {
    const int rA0 = wv * 4 + (lane >> 4);
    colAe = ((lane & 15) << 2) ^ ((rA0 & 7) << 3);
#pragma unroll
    for (int j = 0; j < 8; ++j) {
      const int grow = min(bm * 128 + rA0 + j * 16, M - 1);
      aSrc[j] = A + (size_t)grow * (size_t)K + colAe;
    }
  }
  const int rB0 = wv * 8 + (lane >> 3);
  const int colB = (((lane & 7) ^ (lane >> 3)) << 3);   // bf16 elems
  const ushort_t* bSrc[4];
#pragma unroll
  for (int j = 0; j < 4; ++j) {
    const int grow = min(bn * 128 + rB0 + j * 32, N - 1);
    bSrc[j] = B + (size_t)grow * (size_t)K + colB;
  }

  for (int kb = kbBeg; kb < kbEnd; ++kb) {
    const int k0 = kb << 6;
    if (AB16 || k0 + 64 <= K) {
      if constexpr (AB16) {
#pragma unroll
        for (int j = 0; j < 4; ++j)
          __builtin_amdgcn_global_load_lds(
              (const __attribute__((address_space(1))) void*)(aSrc[j] + k0),
              (__attribute__((address_space(3))) void*)(AsB + (j * 4 + wv) * 1024),
              16, 0, 0);
      } else {
#pragma unroll
        for (int j = 0; j < 8; ++j)
          __builtin_amdgcn_global_load_lds(
              (const __attribute__((address_space(1))) void*)(aSrc[j] + k0),
              (__attribute__((address_space(3))) void*)(AsB + (j * 4 + wv) * 1024),
              16, 0, 0);
      }
#pragma unroll
      for (int j = 0; j < 4; ++j)
        __builtin_amdgcn_global_load_lds(
            (const __attribute__((address_space(1))) void*)(bSrc[j] + k0),
            (__attribute__((address_space(3))) void*)(BsB + (j * 4 + wv) * 1024),
            16, 0, 0);
    } else if constexpr (!AB16) {
      // K-tail (fp32-A only; K % 8 == 0 so 16B granules suffice)
#pragma unroll
      for (int j = 0; j < 8; ++j) {
        float4 f = make_float4(0.f, 0.f, 0.f, 0.f);
        if (k0 + colAe + 4 <= K) f = *(const float4*)(aSrc[j] + k0);
        *(float4*)(AsB + (j * 4 + wv) * 1024 + lane * 16) = f;
      }
#pragma unroll
      for (int j = 0; j < 4; ++j) {
        u32x4 v = {0u, 0u, 0u, 0u};
        if (k0 + colB + 8 <= K) v = *(const u32x4*)(bSrc[j] + k0);
        *(u32x4*)(BsB + (j * 4 + wv) * 1024 + lane * 16) = v;
      }
    }
    __syncthreads();
#pragma unroll
    for (int kk = 0; kk < 2; ++kk) {
      bf16x8 af[4], bfr[4];
#pragma unroll
      for (int i = 0; i < 4; ++i) {
        const int ra = wr + i * 16 + lrow;
        if constexpr (AB16) {
          af[i] = *(const bf16x8*)(AsB + ra * 128 + ((((kk << 2) + kg) ^ (ra & 7)) << 4));
        } else {
          const char* pa = AsB + ra * 256 + ((kk * 128 + (kg << 5)) ^ ((ra & 7) << 5));
          af[i] = cvt_bf16x8(*(const f32x4*)pa, *(const f32x4*)(pa + 16));
        }
        const int rb = wc + i * 16 + lrow;
        bfr[i] = *(const bf16x8*)(BsB + rb * 128 + ((((kk << 2) + kg) ^ (rb & 7)) << 4));
      }
#pragma unroll
      for (int i = 0; i < 4; ++i)
#pragma unroll
        for (int j = 0; j < 4; ++j)
          acc[i][j] = __builtin_amdgcn_mfma_f32_16x16x32_bf16(af[i], bfr[j], acc[i][j], 0, 0, 0);
    }
    __syncthreads();
  }

  const size_t zoff = (SPLITZ > 1 || DUALB) ? (size_t)z * (size_t)M * (size_t)N : 0;
#pragma unroll
  for (int i = 0; i < 4; ++i) {
#pragma unroll
    for (int j = 0; j < 4; ++j) {
      const int col = bn * 128 + wc + j * 16 + lrow;
      if (col >= N) continue;
      const int row0 = bm * 128 + wr + i * 16 + kg * 4;
      float bv = 0.f;
      if (BIAS) bv = bias[col];
#pragma unroll
      for (int rr = 0; rr < 4; ++rr) {
        const int gr = row0 + rr;
        if (gr < M) {
          const float v = acc[i][j][rr] + bv;
          if constexpr (std::is_same<OutT, __half>::value)
            C[zoff + (size_t)gr * (size_t)N + col] = __float2half(v);
          else
            C[zoff + (size_t)gr * (size_t)N + col] = v;
        }
      }
    }
  }
}

// ---------------- fp32 -> bf16 convert (8 elems/thread)
__global__ __launch_bounds__(256) void f2b(
    const float4* __restrict__ in, u32x4* __restrict__ out, int n8)
{
  const int i = blockIdx.x * 256 + threadIdx.x;
  if (i < n8) {
    const float4 a = in[2 * i], b = in[2 * i + 1];
    u32x4 o = { pack_bf16(a.x, a.y), pack_bf16(a.z, a.w),
                pack_bf16(b.x, b.y), pack_bf16(b.z, b.w) };
    out[i] = o;
  }
}

// ------- fused: sum 6 split-K partials + bias + LN + GELU + l2norm -> hx(f32)+hxb(bf16)
__global__ __launch_bounds__(256) void gee_fuse_ln1(
    const float* __restrict__ P, const float* __restrict__ b_enc,
    const float* __restrict__ g1, const float* __restrict__ b1,
    float* __restrict__ hx, unsigned int* __restrict__ hxb)
{
  const int row = blockIdx.x, tid = threadIdx.x;
  __shared__ float red[16];
  const size_t MN = (size_t)4096 * 512;
  const size_t o2 = (size_t)row * 256 + tid;   // float2 index
  float2 v = ((const float2*)b_enc)[tid];
#pragma unroll
  for (int qq = 0; qq < 6; ++qq) {
    const float2 p = ((const float2*)P)[qq * (MN / 2) + o2];
    v.x += p.x; v.y += p.y;
  }
  float a = v.x + v.y;
  float b = v.x * v.x + v.y * v.y;
#pragma unroll
  for (int o = 32; o > 0; o >>= 1) { a += __shfl_xor(a, o); b += __shfl_xor(b, o); }
  const int lane = tid & 63, wvi = tid >> 6;
  if (lane == 0) { red[wvi] = a; red[8 + wvi] = b; }
  __syncthreads();
  const float mu  = (red[0] + red[1] + red[2] + red[3]) * (1.f / 512.f);
  const float ex2 = (red[8] + red[9] + red[10] + red[11]) * (1.f / 512.f);
  const float inv = rsqrtf(ex2 - mu * mu + 1e-5f);
  const float2 gg = ((const float2*)g1)[tid];
  const float2 bb = ((const float2*)b1)[tid];
  const float y0 = (v.x - mu) * inv * gg.x + bb.x;
  const float y1 = (v.y - mu) * inv * gg.y + bb.y;
  const float t0 = 0.5f * y0 * (1.f + erff(y0 * 0.70710678118654752f));
  const float t1 = 0.5f * y1 * (1.f + erff(y1 * 0.70710678118654752f));
  float ss = t0 * t0 + t1 * t1;
  __syncthreads();
#pragma unroll
  for (int o = 32; o > 0; o >>= 1) ss += __shfl_xor(ss, o);
  if (lane == 0) red[wvi] = ss;
  __syncthreads();
  const float sc = 1.f / fmaxf(sqrtf(red[0] + red[1] + red[2] + red[3]), 1e-12f);
  const float h0 = t0 * sc, h1 = t1 * sc;
  ((float2*)hx)[o2] = make_float2(h0, h1);
  hxb[o2] = pack_bf16(h0, h1);
}

// ---------------- row l2norm of raw e [20000,512] fp16 -> eb bf16
__global__ __launch_bounds__(256) void gee_l2rows(
    const __half2* __restrict__ ein, unsigned int* __restrict__ eb)
{
  const int row = blockIdx.x, tid = threadIdx.x;
  __shared__ float red[4];
  const __half2 h = ein[(size_t)row * 256 + tid];
  const float vx = __half2float(h.x), vy = __half2float(h.y);
  float ss = vx * vx + vy * vy;
#pragma unroll
  for (int o = 32; o > 0; o >>= 1) ss += __shfl_xor(ss, o);
  if ((tid & 63) == 0) red[tid >> 6] = ss;
  __syncthreads();
  const float sc = 1.f / fmaxf(sqrtf(red[0] + red[1] + red[2] + red[3]), 1e-12f);
  eb[(size_t)row * 256 + tid] = pack_bf16(vx * sc, vy * sc);
}

// ---------------- per-row top-64: LDS byte-histogram select + compaction
__global__ __launch_bounds__(256) void gee_topk(
    const __half* __restrict__ scores, int* __restrict__ oidx, float* __restrict__ ow)
{
  constexpr int G = 20000, GP = G / 2, CAP = 2048, TCAP = 160;
  const int row = blockIdx.x, tid = threadIdx.x;
  const int lane = tid & 63, wv = tid >> 6;
  __shared__ int hist[4][256];
  __shared__ int cnt_ge[256];
  __shared__ int wtop[4];
  __shared__ unsigned int comp[CAP];   // (key<<16) | idx
  __shared__ int whist[4][16];
  __shared__ int sel[64];
  __shared__ int tie[TCAP];
  __shared__ int s_thr, s_above, s_cand, s_cnt, s_n1, s_n2;

  const unsigned int* srow32 =
      (const unsigned int*)((const ushort_t*)scores + (size_t)row * G);
  const ushort_t* srow16 = (const ushort_t*)srow32;

#pragma unroll
  for (int b = 0; b < 4; ++b) hist[b][tid] = 0;
  if (tid == 0) { s_cnt = 0; s_n1 = 0; s_n2 = 0; }
  __syncthreads();

  // ---- scan 1: per-wave-privatized 256-bin histogram of the top key byte
  for (int j0 = 0; j0 < GP; j0 += 256) {
    const int j = j0 + tid;
    if (j < GP) {
      const unsigned int p = srow32[j];
      const unsigned int f = (((p >> 15) & 0x10001u) * 0x7FFFu) + 0x80008000u;
      const unsigned int k2 = p ^ f;
      atomicAdd(&hist[wv][(k2 >> 8) & 0xFFu], 1);
      atomicAdd(&hist[wv][k2 >> 24], 1);
    }
  }
  __syncthreads();
  cnt_ge[tid] = hist[0][tid] + hist[1][tid] + hist[2][tid] + hist[3][tid];
  __syncthreads();
  for (int off = 1; off < 256; off <<= 1) {
    const int add = (tid + off < 256) ? cnt_ge[tid + off] : 0;
    __syncthreads();
    cnt_ge[tid] += add;
    __syncthreads();
  }
  {
    const unsigned long long m = __ballot(cnt_ge[tid] >= 64);
    if (lane == 0) wtop[wv] = m ? (wv * 64 + 63 - __clzll(m)) : -1;
  }
  __syncthreads();
  if (tid == 0) {
    const int thrB = max(max(wtop[0], wtop[1]), max(wtop[2], wtop[3]));
    s_cand  = cnt_ge[thrB];
    s_above = (thrB == 255) ? 0 : cnt_ge[thrB + 1];
    s_thr   = thrB << 8;
  }
  __syncthreads();

  const bool useComp = (s_cand <= CAP);
  const unsigned int thrB = ((unsigned int)s_thr) >> 8;

  // ---- scan 2: compact elements with byte >= thrB
  if (useComp) {
    for (int j0 = 0; j0 < GP; j0 += 256) {
      const int j = j0 + tid;
      if (j < GP) {
        const unsigned int p = srow32[j];
        const unsigned int f = (((p >> 15) & 0x10001u) * 0x7FFFu) + 0x80008000u;
        const unsigned int k2 = p ^ f;
        const unsigned int lo = k2 & 0xFFFFu, hi = k2 >> 16;
        if ((lo >> 8) >= thrB) {
          const int pos = atomicAdd(&s_cnt, 1);
          comp[pos] = (lo << 16) | (unsigned)(2 * j);
        }
        if ((hi >> 8) >= thrB) {
          const int pos = atomicAdd(&s_cnt, 1);
          comp[pos] = (hi << 16) | (unsigned)(2 * j + 1);
        }
      }
    }
  }
  __syncthreads();
  const int Nloop = useComp ? s_cnt : G;

  // ---- nibble passes: bits [7:4], [3:0]
  for (int pass = 2; pass < 4; ++pass) {
    const int shift = 12 - 4 * pass;
    const unsigned int thr = (unsigned int)s_thr;
    const unsigned int pfx = thr >> (shift + 4);
    int c[16];
#pragma unroll
    for (int b = 0; b < 16; ++b) c[b] = 0;
    for (int j0 = 0; j0 < Nloop; j0 += 256) {
      const int j = j0 + tid;
      const bool ok = j < Nloop;
      unsigned int key;
      if (useComp) {
        key = ok ? (comp[j] >> 16) : 0u;
      } else {
        const unsigned int raw = ok ? (unsigned int)srow16[j] : 0u;
        key = (raw & 0x8000u) ? (0xFFFFu & ~raw) : (raw | 0x8000u);
      }
      const unsigned int nb = (ok && (key >> (shift + 4)) == pfx) ? ((key >> shift) & 15u) : 0xFFu;
#pragma unroll
      for (int b = 0; b < 16; ++b) c[b] += __popcll(__ballot(nb == (unsigned)b));
    }
    if (lane == 0) {
#pragma unroll
      for (int b = 0; b < 16; ++b) whist[wv][b] = c[b];
    }
    __syncthreads();
    if (tid == 0) {
      int run = s_above;
      for (int vv = 15; vv >= 0; --vv) {
        const int c4 = whist[0][vv] + whist[1][vv] + whist[2][vv] + whist[3][vv];
        if (run + c4 >= 64) { s_thr |= vv << shift; break; }
        run += c4;
      }
      s_above = run;
    }
    __syncthreads();
  }

  // ---- selection
  const unsigned int kthr = (unsigned int)s_thr;
  for (int j0 = 0; j0 < Nloop; j0 += 256) {
    const int j = j0 + tid;
    if (j < Nloop) {
      unsigned int key, idx;
      if (useComp) {
        const unsigned int u = comp[j];
        key = u >> 16; idx = u & 0xFFFFu;
      } else {
        const unsigned int raw = (unsigned int)srow16[j];
        key = (raw & 0x8000u) ? (0xFFFFu & ~raw) : (raw | 0x8000u);
        idx = (unsigned)j;
      }
      if (key > kthr) {
        const int pos = atomicAdd(&s_n1, 1);
        sel[pos] = (int)idx;
      } else if (key == kthr) {
        const int pos = atomicAdd(&s_n2, 1);
        if (pos < TCAP) tie[pos] = (int)idx;
      }
    }
  }
  __syncthreads();
  if (tid == 0) {
    const int n1 = s_n1;
    const int n2 = min(s_n2, TCAP);
    const int need = 64 - n1;
    for (int rr = 0; rr < need; ++rr) {     // smallest indices (top_k tie-break)
      int best = 1 << 30, bj = 0;
      for (int j = 0; j < n2; ++j)
        if (tie[j] < best) { best = tie[j]; bj = j; }
      sel[n1 + rr] = best;
      tie[bj] = 1 << 30;
    }
  }
  __syncthreads();
  if (tid < 64) {
    const int idx = sel[tid];
    const float s = __half2float(scores[(size_t)row * G + idx]) * 10.0f;  // 1/T
    float m = s;
#pragma unroll
    for (int o = 32; o > 0; o >>= 1) m = fmaxf(m, __shfl_xor(m, o));
    const float w = __expf(s - m);
    float d = w;
#pragma unroll
    for (int o = 32; o > 0; o >>= 1) d += __shfl_xor(d, o);
    oidx[(size_t)row * 64 + tid] = idx;
    ow[(size_t)row * 64 + tid] = w / d;
  }
}

// ------- ctx[b] = sum_k attn_k * eb[idx_k]  (bf16 gather/accum fp32 -> bf16 out)
__global__ __launch_bounds__(256) void gee_ctx(
    const int* __restrict__ idx, const float* __restrict__ w,
    const unsigned int* __restrict__ eb, unsigned int* __restrict__ ctxb)
{
  const int row = blockIdx.x, tid = threadIdx.x;
  __shared__ int sidx[64];
  __shared__ float sw[64];
  if (tid < 64) { sidx[tid] = idx[(size_t)row * 64 + tid]; sw[tid] = w[(size_t)row * 64 + tid]; }
  __syncthreads();
  float a0 = 0.f, a1 = 0.f;
#pragma unroll 4
  for (int k = 0; k < 64; ++k) {
    const unsigned int pk = eb[(size_t)sidx[k] * 256 + tid];
    const float wk = sw[k];
    a0 += wk * __uint_as_float(pk << 16);
    a1 += wk * __uint_as_float(pk & 0xFFFF0000u);
  }
  ctxb[(size_t)row * 256 + tid] = pack_bf16(a0, a1);
}

// ---------------- h_cell = (1+gamma)*h_x + beta  -> bf16
__global__ __launch_bounds__(256) void gee_film(
    const float2* __restrict__ gm, const float2* __restrict__ bt,
    const float2* __restrict__ hx, unsigned int* __restrict__ hcb, int n2)
{
  const int i = blockIdx.x * 256 + threadIdx.x;
  if (i < n2) {
    const float2 g = gm[i], b = bt[i], h = hx[i];
    hcb[i] = pack_bf16((1.f + g.x) * h.x + b.x, (1.f + g.y) * h.y + b.y);
  }
}

// ---------------- LN2 + exact GELU -> out [4096,1024]
__global__ __launch_bounds__(256) void gee_ln2(
    const float* __restrict__ h2, const float* __restrict__ g2,
    const float* __restrict__ b2, float* __restrict__ out)
{
  const int row = blockIdx.x, tid = threadIdx.x;
  __shared__ float red[16];
  float v[4];
  float a = 0.f, b = 0.f;
#pragma unroll
  for (int e = 0; e < 4; ++e) {
    v[e] = h2[(size_t)row * 1024 + tid + e * 256];
    a += v[e]; b += v[e] * v[e];
  }
#pragma unroll
  for (int o = 32; o > 0; o >>= 1) { a += __shfl_xor(a, o); b += __shfl_xor(b, o); }
  const int lane = tid & 63, wvi = tid >> 6;
  if (lane == 0) { red[wvi] = a; red[8 + wvi] = b; }
  __syncthreads();
  const float mu  = (red[0] + red[1] + red[2] + red[3]) * (1.f / 1024.f);
  const float ex2 = (red[8] + red[9] + red[10] + red[11]) * (1.f / 1024.f);
  const float inv = rsqrtf(ex2 - mu * mu + 1e-5f);
#pragma unroll
  for (int e = 0; e < 4; ++e) {
    const int c = tid + e * 256;
    const float y = (v[e] - mu) * inv * g2[c] + b2[c];
    out[(size_t)row * 1024 + c] = 0.5f * y * (1.f + erff(y * 0.70710678118654752f));
  }
}

extern "C" void kernel_launch(void* const* d_in, const int* in_sizes, int n_in,
                              void* d_out, int out_size, void* d_ws, size_t ws_size,
                              hipStream_t stream)
{
  const float* x       = (const float*)d_in[0];
  const float* g       = (const float*)d_in[1];
  const float* W_enc   = (const float*)d_in[2];
  const float* b_enc   = (const float*)d_in[3];
  const float* ln1_g   = (const float*)d_in[4];
  const float* ln1_b   = (const float*)d_in[5];
  const float* W_ga    = (const float*)d_in[6];
  const float* W_gamma = (const float*)d_in[7];
  const float* b_gamma = (const float*)d_in[8];
  const float* W_beta  = (const float*)d_in[9];
  const float* b_beta  = (const float*)d_in[10];
  const float* W_exp   = (const float*)d_in[11];
  const float* b_exp   = (const float*)d_in[12];
  const float* ln2_g   = (const float*)d_in[13];
  const float* ln2_b   = (const float*)d_in[14];
  float* out = (float*)d_out;

  char* ws = (char*)d_ws;
  // Region S0 [0,163.84M): part(t1-t2) -> scores(t5-t6) -> ga/be/h2(t8+)
  constexpr size_t OFF_PART   = 0;            // 6*4096*512*4 = 50,331,648
  constexpr size_t OFF_SCORES = 0;            // 163,840,000
  constexpr size_t OFF_GA     = 0;            // 8,388,608
  constexpr size_t OFF_BE     = 8388608;      // 8,388,608 (GA + M*N*4, DUALB)
  constexpr size_t OFF_H2     = 16777216;     // 16,777,216
  constexpr size_t OFF_WENCB  = 163840000;    // 20,480,000 (t0-t1) -> eb (t4-t7)
  constexpr size_t OFF_EB     = 163840000;    // 20,480,000
  constexpr size_t OFF_WGAB   = 184320000;    // 524,288
  constexpr size_t OFF_WGMB   = 184844288;    // 524,288
  constexpr size_t OFF_WBTB   = 185368576;    // 524,288
  constexpr size_t OFF_WEXB   = 185892864;    // 1,048,576
  constexpr size_t OFF_HX     = 186941440;    // 8,388,608  (fp32, for film)
  constexpr size_t OFF_E      = 195330048;    // 20,480,000 (fp16 raw e)
  constexpr size_t OFF_HXB    = 215810048;    // 4,194,304
  constexpr size_t OFF_CTXB   = 220004352;    // 4,194,304
  constexpr size_t OFF_HCB    = 224198656;    // 4,194,304
  constexpr size_t OFF_TIDX   = 228392960;    // 1,048,576
  constexpr size_t OFF_TW     = 229441536;    // 1,048,576 -> total 230,490,112

  float*        part   = (float*)(ws + OFF_PART);
  __half*       scores = (__half*)(ws + OFF_SCORES);
  float*        ga     = (float*)(ws + OFF_GA);
  float*        be     = (float*)(ws + OFF_BE);
  float*        h2     = (float*)(ws + OFF_H2);
  ushort_t*     wencb  = (ushort_t*)(ws + OFF_WENCB);
  unsigned int* eb     = (unsigned int*)(ws + OFF_EB);
  ushort_t*     wgab   = (ushort_t*)(ws + OFF_WGAB);
  ushort_t*     wgmb   = (ushort_t*)(ws + OFF_WGMB);
  ushort_t*     wbtb   = (ushort_t*)(ws + OFF_WBTB);
  ushort_t*     wexb   = (ushort_t*)(ws + OFF_WEXB);
  float*        hx     = (float*)(ws + OFF_HX);
  __half*       e      = (__half*)(ws + OFF_E);
  unsigned int* hxb    = (unsigned int*)(ws + OFF_HXB);
  unsigned int* ctxb   = (unsigned int*)(ws + OFF_CTXB);
  unsigned int* hcb    = (unsigned int*)(ws + OFF_HCB);
  int*          tidx   = (int*)(ws + OFF_TIDX);
  float*        tw     = (float*)(ws + OFF_TW);

  // 0) weight converts fp32 -> bf16
  f2b<<<5000, 256, 0, stream>>>((const float4*)W_enc,   (u32x4*)wencb, 1280000);
  f2b<<<128,  256, 0, stream>>>((const float4*)W_ga,    (u32x4*)wgab,  32768);
  f2b<<<128,  256, 0, stream>>>((const float4*)W_gamma, (u32x4*)wgmb,  32768);
  f2b<<<128,  256, 0, stream>>>((const float4*)W_beta,  (u32x4*)wbtb,  32768);
  f2b<<<256,  256, 0, stream>>>((const float4*)W_exp,   (u32x4*)wexb,  65536);

  // 1) split-K=6 partials of x @ W_enc^T -> part[6][4096][512] (768 blk = 3/CU)
  bgemm<float, 6, false, false, float><<<768, 256, 0, stream>>>(
      x, wencb, nullptr, nullptr, nullptr, part, 4096, 512, 20000, 4, 32);
  // 2) h_x = l2norm(gelu(LN1(sum partials + b_enc)))  -> hx fp32 + hxb bf16
  gee_fuse_ln1<<<4096, 256, 0, stream>>>(part, b_enc, ln1_g, ln1_b, hx, hxb);
  // 3) e_raw = g @ W_ga^T  [20000][512] fp16
  bgemm<float, 1, false, false, __half><<<628, 256, 0, stream>>>(
      g, wgab, nullptr, nullptr, nullptr, e, 20000, 512, 512, 4, 157);
  // 4) eb = l2norm rows (bf16)
  gee_l2rows<<<20000, 256, 0, stream>>>((const __half2*)e, eb);
  // 5) scores = h_x @ eb^T  (bf16-A path, fp16 out)
  bgemm<ushort_t, 1, false, false, __half><<<5024, 256, 0, stream>>>(
      (const ushort_t*)hxb, (const ushort_t*)eb, nullptr, nullptr, nullptr,
      scores, 4096, 20000, 512, 157, 32);
  // 6) top-64 + softmax weights
  gee_topk<<<4096, 256, 0, stream>>>(scores, tidx, tw);
  // 7) ctx = attn-weighted sum of eb rows -> bf16
  gee_ctx<<<4096, 256, 0, stream>>>(tidx, tw, eb, ctxb);
  // 8) FiLM gamma (z=0) / beta (z=1), bf16-A
  bgemm<ushort_t, 1, true, true, float><<<256, 256, 0, stream>>>(
      (const ushort_t*)ctxb, wgmb, wbtb, b_gamma, b_beta, ga, 4096, 512, 512, 4, 32);
  // 9) h_cell = (1+gamma)*h_x + beta -> bf16
  gee_film<<<4096, 256, 0, stream>>>((const float2*)ga, (const float2*)be,
                                     (const float2*)hx, hcb, 1048576);
  // 10) h2 = h_cell @ W_exp^T + b_exp  (bf16-A)
  bgemm<ushort_t, 1, false, true, float><<<256, 256, 0, stream>>>(
      (const ushort_t*)hcb, wexb, nullptr, b_exp, nullptr, h2, 4096, 1024, 512, 8, 32);
  // 11) out = gelu(LN2(h2))
  gee_ln2<<<4096, 256, 0, stream>>>(h2, ln2_g, ln2_b, out);
}